// Round 1
// baseline (743.867 us; speedup 1.0000x reference)
//
#include <hip/hip_runtime.h>
#include <stdint.h>

// Problem constants (from reference)
#define N_TOK 8192
#define HDIM  1024
#define FDIM  4096
#define NEXP  8
#define MAXTILES 72   // worst-case sum of ceil(cnt_e/128) = 64+7 < 72

typedef __attribute__((ext_vector_type(8))) __bf16 bf16x8;
typedef __attribute__((ext_vector_type(8))) unsigned short ushort8v;
typedef __attribute__((ext_vector_type(4))) unsigned short ushort4v;
typedef __attribute__((ext_vector_type(4))) float floatx4;

// f32 -> bf16 round-to-nearest-even (bit trick; NaN path irrelevant here)
__device__ __forceinline__ unsigned short f2bf(float f) {
  union { float f; uint32_t u; } v; v.f = f;
  uint32_t u = v.u;
  return (unsigned short)((u + 0x7FFFu + ((u >> 16) & 1u)) >> 16);
}

// async global->LDS, 16B per lane. LDS dest is wave-uniform base + lane*16.
__device__ __forceinline__ void load_lds16(const void* g, void* l) {
  __builtin_amdgcn_global_load_lds(
      (const __attribute__((address_space(1))) void*)(uintptr_t)g,
      (__attribute__((address_space(3))) void*)(uint32_t)(uintptr_t)l,
      16, 0, 0);
}

// ws int layout: [0..7]=counts [8..15]=offsets [16..23]=cursors [24]=ntiles
// [32..103]=tile list (e<<16|mt). order[] at int offset 256 (N ints).
// xs (bf16, sorted) at byte 65536; h1 (bf16) after xs.

__global__ void k_count(const int* __restrict__ experts, int* __restrict__ meta) {
  int i = blockIdx.x * 256 + threadIdx.x;
  atomicAdd(&meta[experts[i]], 1);
}

__global__ void k_plan(int* __restrict__ meta) {
  if (threadIdx.x == 0) {
    int off = 0, nt = 0;
    for (int e = 0; e < NEXP; ++e) {
      int c = meta[e];
      meta[8 + e] = off;
      meta[16 + e] = off;     // cursor starts at segment offset
      int t = (c + 127) >> 7;
      for (int k = 0; k < t; ++k) meta[32 + nt++] = (e << 16) | k;
      off += c;
    }
    meta[24] = nt;
  }
}

__global__ void k_scatter(const int* __restrict__ experts, int* __restrict__ meta,
                          int* __restrict__ order) {
  int i = blockIdx.x * 256 + threadIdx.x;
  int e = experts[i];
  int pos = atomicAdd(&meta[16 + e], 1);  // absolute slot (cursor pre-offset)
  order[pos] = i;
}

// pack x rows into sorted order as bf16: xs[s][:] = bf16(x[order[s]][:])
__global__ void k_pack(const float* __restrict__ x, const int* __restrict__ order,
                       unsigned short* __restrict__ xs) {
  int s = blockIdx.x;
  int i = order[s];
  int t = threadIdx.x;
  float4 v = *(const float4*)(x + (size_t)i * HDIM + t * 4);
  ushort4v u;
  u[0] = f2bf(v.x); u[1] = f2bf(v.y); u[2] = f2bf(v.z); u[3] = f2bf(v.w);
  *(ushort4v*)(xs + (size_t)s * HDIM + t * 4) = u;
}

// ---------------- GEMM1: h1[s][f] = gelu( sum_h xs[s][h] * w1[e][f][h] ) ----------------
// NT gemm, tile 128x128, BK=32, 4 waves in 2x2, 16x16x32 bf16 MFMA.
__global__ __launch_bounds__(256) void gemm1(
    const unsigned short* __restrict__ xs, const float* __restrict__ w1,
    unsigned short* __restrict__ h1, const int* __restrict__ meta) {
  __shared__ unsigned short As[128 * 32];
  __shared__ unsigned short Bs[128 * 32];

  int bx = blockIdx.x;
  if (bx >= meta[24]) return;
  int entry = meta[32 + bx];
  int e = entry >> 16, mt = entry & 0xffff;
  int row0 = meta[8 + e] + mt * 128;
  int rend = meta[8 + e] + meta[e];
  int fBase = blockIdx.y * 128;

  int tid = threadIdx.x;
  int w = tid >> 6, lane = tid & 63;
  int r = lane & 15, q = lane >> 4;
  int wm = (w >> 1) * 64, wn = (w & 1) * 64;

  // B staging: thread covers w1 row (fBase+brow), 16 consecutive k at bkk
  int brow = tid >> 1;
  int bkk = (tid & 1) * 16;
  const float* wbase = w1 + ((size_t)e * FDIM + fBase + brow) * HDIM + bkk;

  // A staging via global_load_lds: 2 issues/thread, lane l -> LDS base + l*16
  int ar0 = (w * 16) + (lane >> 2);
  int ar1 = 64 + ar0;
  int s0 = min(row0 + ar0, N_TOK - 1);
  int s1 = min(row0 + ar1, N_TOK - 1);
  const unsigned short* ag0 = xs + (size_t)s0 * HDIM + (lane & 3) * 8;
  const unsigned short* ag1 = xs + (size_t)s1 * HDIM + (lane & 3) * 8;
  unsigned short* al0 = &As[(w * 16) * 32];
  unsigned short* al1 = &As[(64 + w * 16) * 32];

  floatx4 acc[4][4];
#pragma unroll
  for (int i = 0; i < 4; ++i)
#pragma unroll
    for (int j = 0; j < 4; ++j) acc[i][j] = (floatx4){0.f, 0.f, 0.f, 0.f};

  for (int k0 = 0; k0 < HDIM; k0 += 32) {
    __syncthreads();
    load_lds16(ag0 + k0, al0);
    load_lds16(ag1 + k0, al1);
    const float* gb = wbase + k0;
    float4 f0 = *(const float4*)(gb);
    float4 f1 = *(const float4*)(gb + 4);
    float4 f2 = *(const float4*)(gb + 8);
    float4 f3 = *(const float4*)(gb + 12);
    ushort8v u0, u1;
    u0[0] = f2bf(f0.x); u0[1] = f2bf(f0.y); u0[2] = f2bf(f0.z); u0[3] = f2bf(f0.w);
    u0[4] = f2bf(f1.x); u0[5] = f2bf(f1.y); u0[6] = f2bf(f1.z); u0[7] = f2bf(f1.w);
    u1[0] = f2bf(f2.x); u1[1] = f2bf(f2.y); u1[2] = f2bf(f2.z); u1[3] = f2bf(f2.w);
    u1[4] = f2bf(f3.x); u1[5] = f2bf(f3.y); u1[6] = f2bf(f3.z); u1[7] = f2bf(f3.w);
    *(ushort8v*)&Bs[brow * 32 + bkk] = u0;
    *(ushort8v*)&Bs[brow * 32 + bkk + 8] = u1;
    __syncthreads();

    bf16x8 av[4], bv[4];
#pragma unroll
    for (int i = 0; i < 4; ++i)
      av[i] = __builtin_bit_cast(bf16x8, *(const ushort8v*)&As[(wm + i * 16 + r) * 32 + q * 8]);
#pragma unroll
    for (int j = 0; j < 4; ++j)
      bv[j] = __builtin_bit_cast(bf16x8, *(const ushort8v*)&Bs[(wn + j * 16 + r) * 32 + q * 8]);
#pragma unroll
    for (int i = 0; i < 4; ++i)
#pragma unroll
      for (int j = 0; j < 4; ++j)
        acc[i][j] = __builtin_amdgcn_mfma_f32_16x16x32_bf16(av[i], bv[j], acc[i][j], 0, 0, 0);
  }

  // epilogue: exact gelu, store bf16. D: row = q*4+reg, col = r.
#pragma unroll
  for (int i = 0; i < 4; ++i) {
    int mrow = row0 + wm + i * 16 + q * 4;
#pragma unroll
    for (int reg = 0; reg < 4; ++reg) {
      int s = mrow + reg;
      if (s < rend) {
        unsigned short* dst = h1 + (size_t)s * FDIM + fBase + wn + r;
#pragma unroll
        for (int j = 0; j < 4; ++j) {
          float v = acc[i][j][reg];
          float g = 0.5f * v * (1.0f + erff(v * 0.70710678118654752f));
          dst[j * 16] = f2bf(g);
        }
      }
    }
  }
}

// ---- GEMM2: y[s][hh] = sum_f h1[s][f]*w2[e][hh][f]; fused gate+scatter+pair-reduce ----
__global__ __launch_bounds__(256) void gemm2(
    const unsigned short* __restrict__ h1, const float* __restrict__ w2,
    const float* __restrict__ gate, const int* __restrict__ new_index,
    float* __restrict__ out, const int* __restrict__ meta) {
  __shared__ unsigned short As[128 * 32];
  __shared__ unsigned short Bs[128 * 32];

  int bx = blockIdx.x;
  if (bx >= meta[24]) return;
  int entry = meta[32 + bx];
  int e = entry >> 16, mt = entry & 0xffff;
  int row0 = meta[8 + e] + mt * 128;
  int rend = meta[8 + e] + meta[e];
  int nBase = blockIdx.y * 128;
  const int* order = meta + 256;

  int tid = threadIdx.x;
  int w = tid >> 6, lane = tid & 63;
  int r = lane & 15, q = lane >> 4;
  int wm = (w >> 1) * 64, wn = (w & 1) * 64;

  int brow = tid >> 1;
  int bkk = (tid & 1) * 16;
  const float* wbase = w2 + ((size_t)e * HDIM + nBase + brow) * FDIM + bkk;

  int ar0 = (w * 16) + (lane >> 2);
  int ar1 = 64 + ar0;
  int s0 = min(row0 + ar0, N_TOK - 1);
  int s1 = min(row0 + ar1, N_TOK - 1);
  const unsigned short* ag0 = h1 + (size_t)s0 * FDIM + (lane & 3) * 8;
  const unsigned short* ag1 = h1 + (size_t)s1 * FDIM + (lane & 3) * 8;
  unsigned short* al0 = &As[(w * 16) * 32];
  unsigned short* al1 = &As[(64 + w * 16) * 32];

  floatx4 acc[4][4];
#pragma unroll
  for (int i = 0; i < 4; ++i)
#pragma unroll
    for (int j = 0; j < 4; ++j) acc[i][j] = (floatx4){0.f, 0.f, 0.f, 0.f};

  for (int k0 = 0; k0 < FDIM; k0 += 32) {
    __syncthreads();
    load_lds16(ag0 + k0, al0);
    load_lds16(ag1 + k0, al1);
    const float* gb = wbase + k0;
    float4 f0 = *(const float4*)(gb);
    float4 f1 = *(const float4*)(gb + 4);
    float4 f2 = *(const float4*)(gb + 8);
    float4 f3 = *(const float4*)(gb + 12);
    ushort8v u0, u1;
    u0[0] = f2bf(f0.x); u0[1] = f2bf(f0.y); u0[2] = f2bf(f0.z); u0[3] = f2bf(f0.w);
    u0[4] = f2bf(f1.x); u0[5] = f2bf(f1.y); u0[6] = f2bf(f1.z); u0[7] = f2bf(f1.w);
    u1[0] = f2bf(f2.x); u1[1] = f2bf(f2.y); u1[2] = f2bf(f2.z); u1[3] = f2bf(f2.w);
    u1[4] = f2bf(f3.x); u1[5] = f2bf(f3.y); u1[6] = f2bf(f3.z); u1[7] = f2bf(f3.w);
    *(ushort8v*)&Bs[brow * 32 + bkk] = u0;
    *(ushort8v*)&Bs[brow * 32 + bkk + 8] = u1;
    __syncthreads();

    bf16x8 av[4], bv[4];
#pragma unroll
    for (int i = 0; i < 4; ++i)
      av[i] = __builtin_bit_cast(bf16x8, *(const ushort8v*)&As[(wm + i * 16 + r) * 32 + q * 8]);
#pragma unroll
    for (int j = 0; j < 4; ++j)
      bv[j] = __builtin_bit_cast(bf16x8, *(const ushort8v*)&Bs[(wn + j * 16 + r) * 32 + q * 8]);
#pragma unroll
    for (int i = 0; i < 4; ++i)
#pragma unroll
      for (int j = 0; j < 4; ++j)
        acc[i][j] = __builtin_amdgcn_mfma_f32_16x16x32_bf16(av[i], bv[j], acc[i][j], 0, 0, 0);
  }

  // epilogue: out[new_index[i]>>1][col] += gate[i]*y  (2 contributions/element)
#pragma unroll
  for (int i = 0; i < 4; ++i) {
    int mrow = row0 + wm + i * 16 + q * 4;
#pragma unroll
    for (int reg = 0; reg < 4; ++reg) {
      int s = mrow + reg;
      if (s < rend) {
        int itok = order[s];
        float gw = gate[itok];
        int jdx = new_index[itok];
        float* dst = out + (size_t)(jdx >> 1) * HDIM + nBase + wn + r;
#pragma unroll
        for (int j = 0; j < 4; ++j) atomicAdd(dst + j * 16, acc[i][j][reg] * gw);
      }
    }
  }
}

extern "C" void kernel_launch(void* const* d_in, const int* in_sizes, int n_in,
                              void* d_out, int out_size, void* d_ws, size_t ws_size,
                              hipStream_t stream) {
  const float* x        = (const float*)d_in[0];
  const float* gate     = (const float*)d_in[1];
  const int* experts    = (const int*)d_in[2];
  const int* new_index  = (const int*)d_in[3];
  const float* w1       = (const float*)d_in[4];
  const float* w2       = (const float*)d_in[5];
  float* out            = (float*)d_out;

  int* meta = (int*)d_ws;
  int* order = meta + 256;
  unsigned short* xs = (unsigned short*)((char*)d_ws + 65536);
  unsigned short* h1 = (unsigned short*)((char*)d_ws + 65536 + (size_t)N_TOK * HDIM * 2);
  size_t need = 65536 + (size_t)N_TOK * HDIM * 2 + (size_t)N_TOK * FDIM * 2;
  if (ws_size < need) return;  // insufficient scratch: fail cleanly (absmax check)

  hipMemsetAsync(d_ws, 0, 4096, stream);
  hipMemsetAsync(d_out, 0, (size_t)out_size * sizeof(float), stream);
  k_count<<<N_TOK / 256, 256, 0, stream>>>(experts, meta);
  k_plan<<<1, 64, 0, stream>>>(meta);
  k_scatter<<<N_TOK / 256, 256, 0, stream>>>(experts, meta, order);
  k_pack<<<N_TOK, 256, 0, stream>>>(x, order, xs);
  gemm1<<<dim3(MAXTILES, FDIM / 128), 256, 0, stream>>>(xs, w1, h1, meta);
  gemm2<<<dim3(MAXTILES, HDIM / 128), 256, 0, stream>>>(h1, w2, gate, new_index, out, meta);
}

// Round 2
// 674.674 us; speedup vs baseline: 1.1026x; 1.1026x over previous
//
#include <hip/hip_runtime.h>
#include <stdint.h>

// Problem constants (from reference)
#define N_TOK 8192
#define HDIM  1024
#define FDIM  4096
#define NEXP  8
#define MAXTILES 72   // worst-case sum of ceil(cnt_e/128) = 64+7 < 72

typedef __attribute__((ext_vector_type(8))) __bf16 bf16x8;
typedef __attribute__((ext_vector_type(8))) unsigned short ushort8v;
typedef __attribute__((ext_vector_type(4))) unsigned short ushort4v;
typedef __attribute__((ext_vector_type(4))) float floatx4;

// f32 -> bf16 round-to-nearest-even
__device__ __forceinline__ unsigned short f2bf(float f) {
  union { float f; uint32_t u; } v; v.f = f;
  uint32_t u = v.u;
  return (unsigned short)((u + 0x7FFFu + ((u >> 16) & 1u)) >> 16);
}

// async global->LDS, 16B per lane. LDS dest is wave-uniform base + lane*16.
__device__ __forceinline__ void load_lds16(const void* g, void* l) {
  __builtin_amdgcn_global_load_lds(
      (const __attribute__((address_space(1))) void*)(uintptr_t)g,
      (__attribute__((address_space(3))) void*)(uint32_t)(uintptr_t)l,
      16, 0, 0);
}

// ws int layout: [0..7]=counts [8..15]=offsets [16..23]=cursors [24]=ntiles
// [32..103]=tile list (e<<16|mt). order[] at int offset 256 (N ints).
// Then (byte offsets): xs@65536 (16MB), h1 (64MB), w1b (64MB), w2b (64MB).

__global__ void k_count(const int* __restrict__ experts, int* __restrict__ meta) {
  int i = blockIdx.x * 256 + threadIdx.x;
  atomicAdd(&meta[experts[i]], 1);
}

__global__ void k_plan(int* __restrict__ meta) {
  if (threadIdx.x == 0) {
    int off = 0, nt = 0;
    for (int e = 0; e < NEXP; ++e) {
      int c = meta[e];
      meta[8 + e] = off;
      meta[16 + e] = off;
      int t = (c + 127) >> 7;
      for (int k = 0; k < t; ++k) meta[32 + nt++] = (e << 16) | k;
      off += c;
    }
    meta[24] = nt;
  }
}

__global__ void k_scatter(const int* __restrict__ experts, int* __restrict__ meta,
                          int* __restrict__ order) {
  int i = blockIdx.x * 256 + threadIdx.x;
  int e = experts[i];
  int pos = atomicAdd(&meta[16 + e], 1);
  order[pos] = i;
}

__global__ void k_pack(const float* __restrict__ x, const int* __restrict__ order,
                       unsigned short* __restrict__ xs) {
  int s = blockIdx.x;
  int i = order[s];
  int t = threadIdx.x;
  float4 v = *(const float4*)(x + (size_t)i * HDIM + t * 4);
  ushort4v u;
  u[0] = f2bf(v.x); u[1] = f2bf(v.y); u[2] = f2bf(v.z); u[3] = f2bf(v.w);
  *(ushort4v*)(xs + (size_t)s * HDIM + t * 4) = u;
}

// bulk f32 -> bf16 weight conversion: one float4 per thread
__global__ void k_cvt(const float* __restrict__ src, unsigned short* __restrict__ dst) {
  size_t i = ((size_t)blockIdx.x * 256 + threadIdx.x) * 4;
  float4 v = *(const float4*)(src + i);
  ushort4v u;
  u[0] = f2bf(v.x); u[1] = f2bf(v.y); u[2] = f2bf(v.z); u[3] = f2bf(v.w);
  *(ushort4v*)(dst + i) = u;
}

// ---------------- GEMM1: h1[s][f] = gelu( sum_h xs[s][h] * w1[e][f][h] ) ----------------
// NT gemm, tile 128x128, BK=32, 4 waves 2x2, 16x16x32 bf16 MFMA.
// grid (FDIM/128, 1, MAXTILES): x = fBase slice, z = expert-tile (z slowest so
// consecutive blocks share the A tile -> L2 locality for xs re-reads).
template <bool PRE>
__global__ __launch_bounds__(256) void gemm1_t(
    const unsigned short* __restrict__ xs, const void* __restrict__ w1v,
    unsigned short* __restrict__ h1, const int* __restrict__ meta) {
  __shared__ unsigned short As[128 * 32];
  __shared__ unsigned short Bs[128 * 32];

  int bx = blockIdx.z;
  if (bx >= meta[24]) return;
  int entry = meta[32 + bx];
  int e = entry >> 16, mt = entry & 0xffff;
  int row0 = meta[8 + e] + mt * 128;
  int rend = meta[8 + e] + meta[e];
  int fBase = blockIdx.x * 128;

  int tid = threadIdx.x;
  int w = tid >> 6, lane = tid & 63;
  int r = lane & 15, q = lane >> 4;
  int wm = (w >> 1) * 64, wn = (w & 1) * 64;

  // A staging via global_load_lds
  int ar0 = (w * 16) + (lane >> 2);
  int s0 = min(row0 + ar0, N_TOK - 1);
  int s1 = min(row0 + 64 + ar0, N_TOK - 1);
  const unsigned short* ag0 = xs + (size_t)s0 * HDIM + (lane & 3) * 8;
  const unsigned short* ag1 = xs + (size_t)s1 * HDIM + (lane & 3) * 8;
  unsigned short* al0 = &As[(w * 16) * 32];
  unsigned short* al1 = &As[(64 + w * 16) * 32];

  // B staging pointers
  const unsigned short* bg0 = nullptr; const unsigned short* bg1 = nullptr;
  unsigned short* bl0 = nullptr; unsigned short* bl1 = nullptr;
  const float* wbase = nullptr; int brow = 0, bkk = 0;
  if constexpr (PRE) {
    const unsigned short* wb = (const unsigned short*)w1v;
    int br = w * 16 + (lane >> 2);
    bg0 = wb + ((size_t)e * FDIM + fBase + br) * HDIM + (lane & 3) * 8;
    bg1 = bg0 + (size_t)64 * HDIM;
    bl0 = &Bs[(w * 16) * 32];
    bl1 = &Bs[(64 + w * 16) * 32];
  } else {
    brow = tid >> 1; bkk = (tid & 1) * 16;
    wbase = (const float*)w1v + ((size_t)e * FDIM + fBase + brow) * HDIM + bkk;
  }

  floatx4 acc[4][4];
#pragma unroll
  for (int i = 0; i < 4; ++i)
#pragma unroll
    for (int j = 0; j < 4; ++j) acc[i][j] = (floatx4){0.f, 0.f, 0.f, 0.f};

  for (int k0 = 0; k0 < HDIM; k0 += 32) {
    __syncthreads();
    load_lds16(ag0 + k0, al0);
    load_lds16(ag1 + k0, al1);
    if constexpr (PRE) {
      load_lds16(bg0 + k0, bl0);
      load_lds16(bg1 + k0, bl1);
    } else {
      const float* gb = wbase + k0;
      float4 f0 = *(const float4*)(gb);
      float4 f1 = *(const float4*)(gb + 4);
      float4 f2 = *(const float4*)(gb + 8);
      float4 f3 = *(const float4*)(gb + 12);
      ushort8v u0, u1;
      u0[0] = f2bf(f0.x); u0[1] = f2bf(f0.y); u0[2] = f2bf(f0.z); u0[3] = f2bf(f0.w);
      u0[4] = f2bf(f1.x); u0[5] = f2bf(f1.y); u0[6] = f2bf(f1.z); u0[7] = f2bf(f1.w);
      u1[0] = f2bf(f2.x); u1[1] = f2bf(f2.y); u1[2] = f2bf(f2.z); u1[3] = f2bf(f2.w);
      u1[4] = f2bf(f3.x); u1[5] = f2bf(f3.y); u1[6] = f2bf(f3.z); u1[7] = f2bf(f3.w);
      *(ushort8v*)&Bs[brow * 32 + bkk] = u0;
      *(ushort8v*)&Bs[brow * 32 + bkk + 8] = u1;
    }
    __syncthreads();

    bf16x8 av[4], bv[4];
#pragma unroll
    for (int i = 0; i < 4; ++i)
      av[i] = __builtin_bit_cast(bf16x8, *(const ushort8v*)&As[(wm + i * 16 + r) * 32 + q * 8]);
#pragma unroll
    for (int j = 0; j < 4; ++j)
      bv[j] = __builtin_bit_cast(bf16x8, *(const ushort8v*)&Bs[(wn + j * 16 + r) * 32 + q * 8]);
#pragma unroll
    for (int i = 0; i < 4; ++i)
#pragma unroll
      for (int j = 0; j < 4; ++j)
        acc[i][j] = __builtin_amdgcn_mfma_f32_16x16x32_bf16(av[i], bv[j], acc[i][j], 0, 0, 0);
  }

  // epilogue: exact gelu, store bf16. D: row = q*4+reg, col = r.
#pragma unroll
  for (int i = 0; i < 4; ++i) {
    int mrow = row0 + wm + i * 16 + q * 4;
#pragma unroll
    for (int reg = 0; reg < 4; ++reg) {
      int s = mrow + reg;
      if (s < rend) {
        unsigned short* dst = h1 + (size_t)s * FDIM + fBase + wn + r;
#pragma unroll
        for (int j = 0; j < 4; ++j) {
          float v = acc[i][j][reg];
          float g = 0.5f * v * (1.0f + erff(v * 0.70710678118654752f));
          dst[j * 16] = f2bf(g);
        }
      }
    }
  }
}

// ---- GEMM2: y[s][hh] = sum_f h1[s][f]*w2[e][hh][f]; fused gate+scatter+pair-reduce ----
// grid (HDIM/128, KSPLIT=2, MAXTILES): x = nBase, y = K-half, z = expert-tile.
// K-split is safe because the epilogue accumulates into out via atomicAdd.
template <bool PRE>
__global__ __launch_bounds__(256) void gemm2_t(
    const unsigned short* __restrict__ h1, const void* __restrict__ w2v,
    const float* __restrict__ gate, const int* __restrict__ new_index,
    float* __restrict__ out, const int* __restrict__ meta) {
  __shared__ unsigned short As[128 * 32];
  __shared__ unsigned short Bs[128 * 32];

  int bx = blockIdx.z;
  if (bx >= meta[24]) return;
  int entry = meta[32 + bx];
  int e = entry >> 16, mt = entry & 0xffff;
  int row0 = meta[8 + e] + mt * 128;
  int rend = meta[8 + e] + meta[e];
  int nBase = blockIdx.x * 128;
  int kStart = blockIdx.y * (FDIM / 2);
  int kEnd = kStart + (FDIM / 2);
  const int* order = meta + 256;

  int tid = threadIdx.x;
  int w = tid >> 6, lane = tid & 63;
  int r = lane & 15, q = lane >> 4;
  int wm = (w >> 1) * 64, wn = (w & 1) * 64;

  int ar0 = (w * 16) + (lane >> 2);
  int s0 = min(row0 + ar0, N_TOK - 1);
  int s1 = min(row0 + 64 + ar0, N_TOK - 1);
  const unsigned short* ag0 = h1 + (size_t)s0 * FDIM + (lane & 3) * 8;
  const unsigned short* ag1 = h1 + (size_t)s1 * FDIM + (lane & 3) * 8;
  unsigned short* al0 = &As[(w * 16) * 32];
  unsigned short* al1 = &As[(64 + w * 16) * 32];

  const unsigned short* bg0 = nullptr; const unsigned short* bg1 = nullptr;
  unsigned short* bl0 = nullptr; unsigned short* bl1 = nullptr;
  const float* wbase = nullptr; int brow = 0, bkk = 0;
  if constexpr (PRE) {
    const unsigned short* wb = (const unsigned short*)w2v;
    int br = w * 16 + (lane >> 2);
    bg0 = wb + ((size_t)e * HDIM + nBase + br) * FDIM + (lane & 3) * 8;
    bg1 = bg0 + (size_t)64 * FDIM;
    bl0 = &Bs[(w * 16) * 32];
    bl1 = &Bs[(64 + w * 16) * 32];
  } else {
    brow = tid >> 1; bkk = (tid & 1) * 16;
    wbase = (const float*)w2v + ((size_t)e * HDIM + nBase + brow) * FDIM + bkk;
  }

  floatx4 acc[4][4];
#pragma unroll
  for (int i = 0; i < 4; ++i)
#pragma unroll
    for (int j = 0; j < 4; ++j) acc[i][j] = (floatx4){0.f, 0.f, 0.f, 0.f};

  for (int k0 = kStart; k0 < kEnd; k0 += 32) {
    __syncthreads();
    load_lds16(ag0 + k0, al0);
    load_lds16(ag1 + k0, al1);
    if constexpr (PRE) {
      load_lds16(bg0 + k0, bl0);
      load_lds16(bg1 + k0, bl1);
    } else {
      const float* gb = wbase + k0;
      float4 f0 = *(const float4*)(gb);
      float4 f1 = *(const float4*)(gb + 4);
      float4 f2 = *(const float4*)(gb + 8);
      float4 f3 = *(const float4*)(gb + 12);
      ushort8v u0, u1;
      u0[0] = f2bf(f0.x); u0[1] = f2bf(f0.y); u0[2] = f2bf(f0.z); u0[3] = f2bf(f0.w);
      u0[4] = f2bf(f1.x); u0[5] = f2bf(f1.y); u0[6] = f2bf(f1.z); u0[7] = f2bf(f1.w);
      u1[0] = f2bf(f2.x); u1[1] = f2bf(f2.y); u1[2] = f2bf(f2.z); u1[3] = f2bf(f2.w);
      u1[4] = f2bf(f3.x); u1[5] = f2bf(f3.y); u1[6] = f2bf(f3.z); u1[7] = f2bf(f3.w);
      *(ushort8v*)&Bs[brow * 32 + bkk] = u0;
      *(ushort8v*)&Bs[brow * 32 + bkk + 8] = u1;
    }
    __syncthreads();

    bf16x8 av[4], bv[4];
#pragma unroll
    for (int i = 0; i < 4; ++i)
      av[i] = __builtin_bit_cast(bf16x8, *(const ushort8v*)&As[(wm + i * 16 + r) * 32 + q * 8]);
#pragma unroll
    for (int j = 0; j < 4; ++j)
      bv[j] = __builtin_bit_cast(bf16x8, *(const ushort8v*)&Bs[(wn + j * 16 + r) * 32 + q * 8]);
#pragma unroll
    for (int i = 0; i < 4; ++i)
#pragma unroll
      for (int j = 0; j < 4; ++j)
        acc[i][j] = __builtin_amdgcn_mfma_f32_16x16x32_bf16(av[i], bv[j], acc[i][j], 0, 0, 0);
  }

  // epilogue: out[new_index[i]>>1][col] += gate[i]*y (atomic; 4 adds/element w/ K-split)
#pragma unroll
  for (int i = 0; i < 4; ++i) {
    int mrow = row0 + wm + i * 16 + q * 4;
#pragma unroll
    for (int reg = 0; reg < 4; ++reg) {
      int s = mrow + reg;
      if (s < rend) {
        int itok = order[s];
        float gw = gate[itok];
        int jdx = new_index[itok];
        float* dst = out + (size_t)(jdx >> 1) * HDIM + nBase + wn + r;
#pragma unroll
        for (int j = 0; j < 4; ++j) atomicAdd(dst + j * 16, acc[i][j][reg] * gw);
      }
    }
  }
}

extern "C" void kernel_launch(void* const* d_in, const int* in_sizes, int n_in,
                              void* d_out, int out_size, void* d_ws, size_t ws_size,
                              hipStream_t stream) {
  const float* x        = (const float*)d_in[0];
  const float* gate     = (const float*)d_in[1];
  const int* experts    = (const int*)d_in[2];
  const int* new_index  = (const int*)d_in[3];
  const float* w1       = (const float*)d_in[4];
  const float* w2       = (const float*)d_in[5];
  float* out            = (float*)d_out;

  int* meta = (int*)d_ws;
  int* order = meta + 256;
  const size_t XS_OFF = 65536;
  const size_t XS_SZ  = (size_t)N_TOK * HDIM * 2;          // 16 MB
  const size_t H1_SZ  = (size_t)N_TOK * FDIM * 2;          // 64 MB
  const size_t W_SZ   = (size_t)NEXP * FDIM * HDIM * 2;    // 64 MB each
  unsigned short* xs  = (unsigned short*)((char*)d_ws + XS_OFF);
  unsigned short* h1  = (unsigned short*)((char*)d_ws + XS_OFF + XS_SZ);
  unsigned short* w1b = (unsigned short*)((char*)d_ws + XS_OFF + XS_SZ + H1_SZ);
  unsigned short* w2b = (unsigned short*)((char*)d_ws + XS_OFF + XS_SZ + H1_SZ + W_SZ);
  size_t need_small = XS_OFF + XS_SZ + H1_SZ;
  size_t need_big   = need_small + 2 * W_SZ;
  if (ws_size < need_small) return;
  bool big = ws_size >= need_big;

  hipMemsetAsync(d_ws, 0, 4096, stream);
  hipMemsetAsync(d_out, 0, (size_t)out_size * sizeof(float), stream);
  k_count<<<N_TOK / 256, 256, 0, stream>>>(experts, meta);
  k_plan<<<1, 64, 0, stream>>>(meta);
  k_scatter<<<N_TOK / 256, 256, 0, stream>>>(experts, meta, order);
  k_pack<<<N_TOK, 256, 0, stream>>>(x, order, xs);

  if (big) {
    int nblk = (int)((size_t)NEXP * FDIM * HDIM / 4 / 256);  // 32768
    k_cvt<<<nblk, 256, 0, stream>>>(w1, w1b);
    k_cvt<<<nblk, 256, 0, stream>>>(w2, w2b);
    gemm1_t<true><<<dim3(FDIM / 128, 1, MAXTILES), 256, 0, stream>>>(xs, w1b, h1, meta);
    gemm2_t<true><<<dim3(HDIM / 128, 2, MAXTILES), 256, 0, stream>>>(h1, w2b, gate, new_index, out, meta);
  } else {
    gemm1_t<false><<<dim3(FDIM / 128, 1, MAXTILES), 256, 0, stream>>>(xs, w1, h1, meta);
    gemm2_t<false><<<dim3(HDIM / 128, 2, MAXTILES), 256, 0, stream>>>(h1, w2, gate, new_index, out, meta);
  }
}